// Round 10
// baseline (54.070 us; speedup 1.0000x reference)
//
#include <hip/hip_runtime.h>
#include <hip/hip_bf16.h>

typedef __bf16 bf16x8 __attribute__((ext_vector_type(8)));
typedef float f32x4 __attribute__((ext_vector_type(4)));
typedef unsigned short us8 __attribute__((ext_vector_type(8)));

#define MFMA16 __builtin_amdgcn_mfma_f32_16x16x32_bf16

__device__ __forceinline__ unsigned short f2bf(float f) {
    unsigned int u = __float_as_uint(f);
    u += 0x7fffu + ((u >> 16) & 1u);   // round-to-nearest-even
    return (unsigned short)(u >> 16);
}

// ============ Pass 1 (fused): pack A' = [x | h] along K' and B-hat panels ====
// Frag = 1024 B = 16 rows x 32 k (lane=(kk>>3)*16+row, 8 contig k per lane).
// A': frag index = mb*32 + kb'  (kb' = kb for x, 16+kb for h), mb 0..511.
// B-hat: 3 buffers (R,U,C) of [nb 0..31][kb' 0..31] frags; kb'<16 from Wx_*,
//        kb'>=16 from Wh_*.
__global__ void cvt_all_kernel(const float* __restrict__ x, const float* __restrict__ h,
                               unsigned short* __restrict__ AP,
                               const float* __restrict__ W0, const float* __restrict__ W1,
                               const float* __restrict__ W2, const float* __restrict__ W3,
                               const float* __restrict__ W4, const float* __restrict__ W5,
                               unsigned short* __restrict__ WP) {
    if (blockIdx.x < 4096) {                         // x,h -> A'
        int c = blockIdx.x * 256 + threadIdx.x;      // 0 .. 2^20-1
        int ih = c >> 19;
        const float* src = ih ? h : x;
        int c2 = c & 524287;
        int mb = c2 >> 10, kb = (c2 >> 6) & 15, lane = c2 & 63;
        int r = lane & 15, ko = lane >> 4;
        const float* p = src + (size_t)(mb * 16 + r) * 512 + kb * 32 + ko * 8;
        float4 v0 = *(const float4*)p;
        float4 v1 = *(const float4*)(p + 4);
        us8 o = { f2bf(v0.x), f2bf(v0.y), f2bf(v0.z), f2bf(v0.w),
                  f2bf(v1.x), f2bf(v1.y), f2bf(v1.z), f2bf(v1.w) };
        *((us8*)AP + ((size_t)(mb * 32 + kb + ih * 16) << 6) + lane) = o;
    } else {                                          // weights -> B-hat
        int c = (blockIdx.x - 4096) * 256 + threadIdx.x;   // 0..196607
        int s = c >> 16, c2 = c & 65535;
        int frag = c2 >> 6, lane = c2 & 63;
        int nb = frag >> 5, kbp = frag & 31;
        const float* Wsrc;
        int kb;
        if (kbp < 16) { kb = kbp;      Wsrc = (s == 0) ? W0 : (s == 1) ? W2 : W4; }
        else          { kb = kbp - 16; Wsrc = (s == 0) ? W1 : (s == 1) ? W3 : W5; }
        int cc = lane & 15, ko = lane >> 4;
        int kbase = kb * 32 + ko * 8;
        us8 o;
#pragma unroll
        for (int e = 0; e < 8; ++e)
            o[e] = f2bf(Wsrc[(size_t)(kbase + e) * 512 + nb * 16 + cc]);
        *((us8*)WP + c) = o;
    }
}

// ============ Pass 2: pure-VGPR fused GEMM + AUGRU epilogue ============
// ZERO LDS, ZERO barriers, ZERO inline asm, ZERO global_load_lds.
// 8 waves (4M x 2N), wave tile 64r x 32c, block 256r x 64c, BK=32, 32 tiles.
// All operands are plain vector loads; explicit 1-deep register rotate;
// compiler owns waitcnt insertion and pipelining (clean dependence graph).
// Same-wc waves share B addresses, same-wr waves share A addresses -> L1
// dedup; distinct L2 traffic ~22 KB/tile/CU.
__global__ __launch_bounds__(512, 2) void augru_mm(
    const unsigned short* __restrict__ AP_,
    const unsigned short* __restrict__ WP_,   // 3 x 1 MiB (R,U,C)
    const float* __restrict__ b_r, const float* __restrict__ b_u, const float* __restrict__ b_h,
    const float* __restrict__ att, const float* __restrict__ h32,
    float* __restrict__ out) {
    const unsigned char* __restrict__ APb = (const unsigned char*)AP_;
    const unsigned char* __restrict__ WPb = (const unsigned char*)WP_;

    const int t0 = threadIdx.x, wv = t0 >> 6, lane = t0 & 63;
    const int laneoff = lane * 16;

    // bijective XCD swizzle: XCD x owns Wid in [32x, 32x+32) -> 4 m-panels
    const int bid = blockIdx.x;               // 0..255
    const int Wid = (bid & 7) * 32 + (bid >> 3);
    const int mblk = Wid >> 3, nblk = Wid & 7;
    const int wr = wv >> 1, wc = wv & 1;      // 4M x 2N wave grid

    f32x4 accR[4][2] = {}, accU[4][2] = {}, accXH[4][2] = {}, accHH[4][2] = {};

    const unsigned char* __restrict__ pA[4];
    const unsigned char* __restrict__ pB[3][2];
#pragma unroll
    for (int mf = 0; mf < 4; ++mf)
        pA[mf] = APb + ((size_t)((mblk * 16 + wr * 4 + mf) * 32) << 10) + laneoff;
#pragma unroll
    for (int s = 0; s < 3; ++s)
#pragma unroll
        for (int nf = 0; nf < 2; ++nf)
            pB[s][nf] = WPb + (size_t)s * 1048576 +
                        ((size_t)((nblk * 4 + wc * 2 + nf) * 32) << 10) + laneoff;

    bf16x8 aN[4], bN[3][2];                   // "next" operand set (rotate)
#pragma unroll
    for (int mf = 0; mf < 4; ++mf) aN[mf] = *(const bf16x8*)(pA[mf]);
#pragma unroll
    for (int s = 0; s < 3; ++s)
#pragma unroll
        for (int nf = 0; nf < 2; ++nf) bN[s][nf] = *(const bf16x8*)(pB[s][nf]);

#define ROTATE_LOAD(T1) { \
    _Pragma("unroll") for (int mf = 0; mf < 4; ++mf) \
        aN[mf] = *(const bf16x8*)(pA[mf] + ((size_t)(T1) << 10)); \
    _Pragma("unroll") for (int s = 0; s < 3; ++s) \
      _Pragma("unroll") for (int nf = 0; nf < 2; ++nf) \
        bN[s][nf] = *(const bf16x8*)(pB[s][nf] + ((size_t)(T1) << 10)); }

#define MFMAS(ACCC) { \
    _Pragma("unroll") for (int mf = 0; mf < 4; ++mf) \
      _Pragma("unroll") for (int nf = 0; nf < 2; ++nf) { \
        accR[mf][nf] = MFMA16(aC[mf], bC[0][nf], accR[mf][nf], 0, 0, 0); \
        accU[mf][nf] = MFMA16(aC[mf], bC[1][nf], accU[mf][nf], 0, 0, 0); \
        ACCC[mf][nf] = MFMA16(aC[mf], bC[2][nf], ACCC[mf][nf], 0, 0, 0); } }

#pragma unroll 2
    for (int T = 0; T < 16; ++T) {            // x-half -> accXH
        bf16x8 aC[4], bC[3][2];
#pragma unroll
        for (int mf = 0; mf < 4; ++mf) aC[mf] = aN[mf];
#pragma unroll
        for (int s = 0; s < 3; ++s)
#pragma unroll
            for (int nf = 0; nf < 2; ++nf) bC[s][nf] = bN[s][nf];
        ROTATE_LOAD(T + 1)
        MFMAS(accXH)
    }
#pragma unroll 2
    for (int T = 16; T < 31; ++T) {           // h-half -> accHH
        bf16x8 aC[4], bC[3][2];
#pragma unroll
        for (int mf = 0; mf < 4; ++mf) aC[mf] = aN[mf];
#pragma unroll
        for (int s = 0; s < 3; ++s)
#pragma unroll
            for (int nf = 0; nf < 2; ++nf) bC[s][nf] = bN[s][nf];
        ROTATE_LOAD(T + 1)
        MFMAS(accHH)
    }
    {                                         // tile 31 (no further load)
        bf16x8 aC[4], bC[3][2];
#pragma unroll
        for (int mf = 0; mf < 4; ++mf) aC[mf] = aN[mf];
#pragma unroll
        for (int s = 0; s < 3; ++s)
#pragma unroll
            for (int nf = 0; nf < 2; ++nf) bC[s][nf] = bN[s][nf];
        MFMAS(accHH)
    }

    // epilogue: C/D layout col=lane&15, row=(lane>>4)*4+reg  [m89-verified]
    const int lr = lane & 15, lg = lane >> 4;
#pragma unroll
    for (int nf = 0; nf < 2; ++nf) {
        const int col = nblk * 64 + wc * 32 + nf * 16 + lr;
        const float br = b_r[col], bu = b_u[col], bh = b_h[col];
#pragma unroll
        for (int mf = 0; mf < 4; ++mf) {
            const int rowb = mblk * 256 + wr * 64 + mf * 16 + lg * 4;
#pragma unroll
            for (int q = 0; q < 4; ++q) {
                const int row = rowb + q;
                float r = 1.f / (1.f + __expf(-(accR[mf][nf][q] + br)));
                float u = 1.f / (1.f + __expf(-(accU[mf][nf][q] + bu)));
                float ph = accXH[mf][nf][q] + bh + r * accHH[mf][nf][q];
                ph = fminf(fmaxf(ph, -15.f), 15.f);
                float e = __expf(2.f * ph);
                float cal = (e - 1.f) / (e + 1.f);
                float hv = h32[(size_t)row * 512 + col];
                float ua = att[row] * u;
                out[(size_t)row * 512 + col] = fmaf(ua, cal - hv, hv);
            }
        }
    }
#undef ROTATE_LOAD
#undef MFMAS
}

extern "C" void kernel_launch(void* const* d_in, const int* in_sizes, int n_in,
                              void* d_out, int out_size, void* d_ws, size_t ws_size,
                              hipStream_t stream) {
    const float* x    = (const float*)d_in[0];
    const float* h    = (const float*)d_in[1];
    const float* att  = (const float*)d_in[2];
    const float* Wx_r = (const float*)d_in[3];
    const float* b_r  = (const float*)d_in[4];
    const float* Wh_r = (const float*)d_in[5];
    const float* Wx_u = (const float*)d_in[6];
    const float* b_u  = (const float*)d_in[7];
    const float* Wh_u = (const float*)d_in[8];
    const float* Wx_h = (const float*)d_in[9];
    const float* b_h  = (const float*)d_in[10];
    const float* Wh_h = (const float*)d_in[11];
    float* out = (float*)d_out;

    unsigned short* AP = (unsigned short*)d_ws;   // 16 MiB packed [x|h]
    unsigned short* WP = AP + 8388608;            //  3 MiB packed B-hat (R,U,C)

    cvt_all_kernel<<<4864, 256, 0, stream>>>(x, h, AP,
        Wx_r, Wh_r, Wx_u, Wh_u, Wx_h, Wh_h, WP);
    augru_mm<<<256, 512, 0, stream>>>(AP, WP, b_r, b_u, b_h, att, h, out);
}